// Round 1
// baseline (89.552 us; speedup 1.0000x reference)
//
#include <hip/hip_runtime.h>

#define NV   6890
#define NB   64
#define NCOL 192           // NB * 3 output columns per row
#define CAP  512           // LDS nonzero-list capacity (flush path guards overflow)
#define SCALE (1.0f / (64.0f * 6890.0f))

// ---------------------------------------------------------------------------
// Kernel 1: transpose x[b][w][d] -> Xt[w][b*3+d] so per-nonzero gathers are
// one coalesced 768B read per list entry.
// ---------------------------------------------------------------------------
__global__ __launch_bounds__(256) void transpose_x_kernel(
    const float* __restrict__ x, float* __restrict__ Xt) {
  int i = blockIdx.x * blockDim.x + threadIdx.x;
  const int total = NB * NV * 3;
  if (i >= total) return;
  int d = i % 3;
  int w = (i / 3) % NV;
  int b = i / (3 * NV);
  Xt[(size_t)w * NCOL + b * 3 + d] = x[i];
}

// ---------------------------------------------------------------------------
// Kernel 2: one 192-thread block per Laplacian row v.
//  Phase A: scan the dense row, ballot-compact nonzeros into LDS (val, col).
//  Phase B: thread n (= b*3+d) accumulates acc_n = sum_j val_j * X[col_j, n].
//  Then sum(acc^2) over the block -> partials[v] (deterministic, no atomics)
//  or atomicAdd fallback when no workspace is available.
// ---------------------------------------------------------------------------
template <bool USE_XT, bool USE_PARTIALS>
__global__ __launch_bounds__(192) void lap_rows_kernel(
    const float* __restrict__ L,
    const float* __restrict__ X,          // Xt if USE_XT, else raw x
    float* __restrict__ partials,         // used if USE_PARTIALS
    float* __restrict__ out_atomic) {     // used if !USE_PARTIALS
  const int v   = blockIdx.x;
  const int tid = threadIdx.x;
  const int lane = tid & 63;
  const float* __restrict__ row = L + (size_t)v * NV;

  __shared__ float s_val[CAP];
  __shared__ int   s_idx[CAP];
  __shared__ int   s_nnz;
  __shared__ int   s_flush;
  __shared__ float s_w[3];

  if (tid == 0) s_nnz = 0;
  __syncthreads();

  // Per-thread gather base for the non-transposed fallback:
  // x[b*NV*3 + w*3 + d] with b = tid/3, d = tid%3.
  const size_t xbase = (size_t)(tid / 3) * (NV * 3) + (tid % 3);

  float acc = 0.0f;

  for (int base = 0; base < NV; base += NCOL) {
    int col = base + tid;
    float val = (col < NV) ? row[col] : 0.0f;
    bool nz = (val != 0.0f);

    unsigned long long m = __ballot(nz);
    int cnt = __popcll(m);
    int off = 0;
    if (lane == 0 && cnt) off = atomicAdd(&s_nnz, cnt);
    off = __shfl(off, 0);
    if (nz) {
      int before = __popcll(m & ((1ull << lane) - 1ull));
      int p = off + before;
      s_val[p] = val;
      s_idx[p] = col;
    }
    __syncthreads();                                   // A: compaction done
    if (tid == 0) s_flush = (s_nnz > CAP - NCOL) ? s_nnz : 0;
    __syncthreads();                                   // B: decision latched
    int f = s_flush;
    if (f) {                                           // rare overflow flush
      for (int j = 0; j < f; ++j) {
        float xv = USE_XT ? X[(size_t)s_idx[j] * NCOL + tid]
                          : X[xbase + (size_t)s_idx[j] * 3];
        acc = fmaf(s_val[j], xv, acc);
      }
      __syncthreads();                                 // C: reads finished
      if (tid == 0) s_nnz = 0;
      __syncthreads();                                 // D: reset visible
    }
  }

  // Final accumulate over remaining list entries.
  int f = s_nnz;
  for (int j = 0; j < f; ++j) {
    float xv = USE_XT ? X[(size_t)s_idx[j] * NCOL + tid]
                      : X[xbase + (size_t)s_idx[j] * 3];
    acc = fmaf(s_val[j], xv, acc);
  }

  // Row contribution: sum over the 192 columns of acc^2.
  float sq = acc * acc;
  #pragma unroll
  for (int o = 32; o > 0; o >>= 1) sq += __shfl_down(sq, o);  // wave64 reduce
  if (lane == 0) s_w[tid >> 6] = sq;
  __syncthreads();
  if (tid == 0) {
    float r = s_w[0] + s_w[1] + s_w[2];
    if (USE_PARTIALS) partials[v] = r;
    else              atomicAdd(out_atomic, r * SCALE);
  }
}

// ---------------------------------------------------------------------------
// Kernel 3: deterministic fixed-order reduction of the 6890 row partials.
// ---------------------------------------------------------------------------
__global__ __launch_bounds__(256) void reduce_kernel(
    const float* __restrict__ p, float* __restrict__ out) {
  int tid = threadIdx.x;
  float a = 0.0f;
  for (int i = tid; i < NV; i += 256) a += p[i];
  #pragma unroll
  for (int o = 32; o > 0; o >>= 1) a += __shfl_down(a, o);
  __shared__ float s_w[4];
  if ((tid & 63) == 0) s_w[tid >> 6] = a;
  __syncthreads();
  if (tid == 0) out[0] = (s_w[0] + s_w[1] + s_w[2] + s_w[3]) * SCALE;
}

__global__ void zero_out_kernel(float* p) {
  if (threadIdx.x == 0 && blockIdx.x == 0) p[0] = 0.0f;
}

// ---------------------------------------------------------------------------
extern "C" void kernel_launch(void* const* d_in, const int* in_sizes, int n_in,
                              void* d_out, int out_size, void* d_ws, size_t ws_size,
                              hipStream_t stream) {
  const float* x = (const float*)d_in[0];   // [64, 6890, 3] f32
  const float* L = (const float*)d_in[1];   // [6890, 6890] f32
  float* out = (float*)d_out;               // scalar f32

  const size_t xt_bytes   = (size_t)NV * NCOL * sizeof(float);  // ~5.3 MB
  const size_t part_bytes = (size_t)NV * sizeof(float);         // ~27.5 KB

  if (ws_size >= xt_bytes + part_bytes) {
    float* Xt       = (float*)d_ws;
    float* partials = (float*)((char*)d_ws + xt_bytes);
    const int total = NB * NV * 3;
    transpose_x_kernel<<<(total + 255) / 256, 256, 0, stream>>>(x, Xt);
    lap_rows_kernel<true, true><<<NV, NCOL, 0, stream>>>(L, Xt, partials, nullptr);
    reduce_kernel<<<1, 256, 0, stream>>>(partials, out);
  } else if (ws_size >= part_bytes) {
    float* partials = (float*)d_ws;
    lap_rows_kernel<false, true><<<NV, NCOL, 0, stream>>>(L, x, partials, nullptr);
    reduce_kernel<<<1, 256, 0, stream>>>(partials, out);
  } else {
    zero_out_kernel<<<1, 64, 0, stream>>>(out);
    lap_rows_kernel<false, false><<<NV, NCOL, 0, stream>>>(L, x, nullptr, out);
  }
}

// Round 2
// 57.002 us; speedup vs baseline: 1.5711x; 1.5711x over previous
//
#include <hip/hip_runtime.h>

#define NV    6890
#define NB    64
#define NCOL  192            // NB * 3 output columns per row
#define CAP_W 512            // per-wave LDS nonzero-list capacity
#define MAIN4 1722           // aligned float4 count per row ( (NV-2)/4 )
#define SCALE (1.0f / (64.0f * 6890.0f))

// ---------------------------------------------------------------------------
// Kernel 1: transpose x[b][w][d] -> Xt[w][b*3+d] so per-nonzero gathers are
// one coalesced 768B read per list entry.
// ---------------------------------------------------------------------------
__global__ __launch_bounds__(256) void transpose_x_kernel(
    const float* __restrict__ x, float* __restrict__ Xt) {
  int i = blockIdx.x * blockDim.x + threadIdx.x;
  const int total = NB * NV * 3;
  if (i >= total) return;
  int d = i % 3;
  int w = (i / 3) % NV;
  int b = i / (3 * NV);
  Xt[(size_t)w * NCOL + b * 3 + d] = x[i];
}

// ---------------------------------------------------------------------------
// Kernel 2: ONE WAVE per Laplacian row. Zero barriers, zero shared atomics.
//  Scan: float4 loads (16B-aligned via 2-float head/tail fixup), in-wave
//        ballot+popc prefix compaction into a per-wave LDS list. nnz stays
//        wave-uniform (SGPR), order is deterministic.
//  FMA:  lane owns columns {lane, lane+64, lane+128}; ~13 list entries,
//        each a coalesced 3x256B gather from Xt.
// ---------------------------------------------------------------------------
template <bool USE_XT, bool USE_PARTIALS>
__global__ __launch_bounds__(256) void lap_rows_wave_kernel(
    const float* __restrict__ L,
    const float* __restrict__ X,          // Xt if USE_XT, else raw x
    float* __restrict__ partials,
    float* __restrict__ out_atomic) {
  const int lane = threadIdx.x & 63;
  const int wv   = threadIdx.x >> 6;
  const int v    = blockIdx.x * 4 + wv;
  if (v >= NV) return;                    // whole-wave exit; no barriers used

  __shared__ float s_val[4][CAP_W];
  __shared__ int   s_idx[4][CAP_W];
  float* __restrict__ sval = s_val[wv];
  int*   __restrict__ sidx = s_idx[wv];

  const float* __restrict__ row = L + (size_t)v * NV;
  const int head     = (v & 1) ? 2 : 0;            // odd rows: 8B-misaligned start
  const int extraPos = head ? 0 : (NV - 2);        // the 2 floats outside the f4 body
  const float4* __restrict__ m4 = (const float4*)(row + head);

  const unsigned long long lmask = (1ull << lane) - 1ull;

  // Per-lane gather offsets for the non-transposed fallback:
  // column n -> b = n/3, d = n%3 -> x[b*NV*3 + w*3 + d]
  const int n0 = lane, n1 = lane + 64, n2 = lane + 128;
  const size_t o0 = (size_t)(n0 / 3) * (NV * 3) + (n0 % 3);
  const size_t o1 = (size_t)(n1 / 3) * (NV * 3) + (n1 % 3);
  const size_t o2 = (size_t)(n2 / 3) * (NV * 3) + (n2 % 3);

  float a0 = 0.f, a1 = 0.f, a2 = 0.f;
  int nnz = 0;                                     // wave-uniform

  auto apply = [&](int count) {
    for (int j = 0; j < count; ++j) {              // uniform j: LDS broadcast
      float val = sval[j];
      int   col = sidx[j];
      if (USE_XT) {
        const float* __restrict__ xr = X + (size_t)col * NCOL;
        a0 = fmaf(val, xr[n0], a0);
        a1 = fmaf(val, xr[n1], a1);
        a2 = fmaf(val, xr[n2], a2);
      } else {
        const size_t cb = (size_t)col * 3;
        a0 = fmaf(val, X[cb + o0], a0);
        a1 = fmaf(val, X[cb + o1], a1);
        a2 = fmaf(val, X[cb + o2], a2);
      }
    }
  };

  auto push = [&](bool nz, float val, int col) {   // wave-uniform call sites
    unsigned long long m = __ballot(nz);
    if (nz) {
      int pos = nnz + __popcll(m & lmask);
      sval[pos] = val;
      sidx[pos] = col;
    }
    nnz += __popcll(m);                            // uniform
  };

  // 2-float head (odd rows) / tail (even rows)
  {
    const bool act = lane < 2;
    const int  col = extraPos + lane;
    float val = act ? row[col] : 0.f;
    push(act && val != 0.f, val, col);
  }

  // Aligned float4 body: 27 wave-uniform iterations, no barriers.
  for (int it = 0; it < 27; ++it) {
    const int i = it * 64 + lane;
    const bool act = i < MAIN4;
    float4 f = make_float4(0.f, 0.f, 0.f, 0.f);
    if (act) f = m4[i];
    const int cb = head + i * 4;
    push(act && f.x != 0.f, f.x, cb);
    push(act && f.y != 0.f, f.y, cb + 1);
    push(act && f.z != 0.f, f.z, cb + 2);
    push(act && f.w != 0.f, f.w, cb + 3);
    if (nnz > CAP_W - 260) { apply(nnz); nnz = 0; }   // pathological-row guard
  }
  apply(nnz);

  // Row contribution: sum over this wave's 3 columns, then wave-reduce.
  float sq = fmaf(a0, a0, fmaf(a1, a1, a2 * a2));
  #pragma unroll
  for (int o = 32; o > 0; o >>= 1) sq += __shfl_down(sq, o);
  if (lane == 0) {
    if (USE_PARTIALS) partials[v] = sq;
    else              atomicAdd(out_atomic, sq * SCALE);
  }
}

// ---------------------------------------------------------------------------
// Kernel 3: deterministic fixed-order reduction of the 6890 row partials.
// ---------------------------------------------------------------------------
__global__ __launch_bounds__(256) void reduce_kernel(
    const float* __restrict__ p, float* __restrict__ out) {
  int tid = threadIdx.x;
  float a = 0.0f;
  for (int i = tid; i < NV; i += 256) a += p[i];
  #pragma unroll
  for (int o = 32; o > 0; o >>= 1) a += __shfl_down(a, o);
  __shared__ float s_w[4];
  if ((tid & 63) == 0) s_w[tid >> 6] = a;
  __syncthreads();
  if (tid == 0) out[0] = (s_w[0] + s_w[1] + s_w[2] + s_w[3]) * SCALE;
}

__global__ void zero_out_kernel(float* p) {
  if (threadIdx.x == 0 && blockIdx.x == 0) p[0] = 0.0f;
}

// ---------------------------------------------------------------------------
extern "C" void kernel_launch(void* const* d_in, const int* in_sizes, int n_in,
                              void* d_out, int out_size, void* d_ws, size_t ws_size,
                              hipStream_t stream) {
  const float* x = (const float*)d_in[0];   // [64, 6890, 3] f32
  const float* L = (const float*)d_in[1];   // [6890, 6890] f32
  float* out = (float*)d_out;               // scalar f32

  const size_t xt_bytes   = (size_t)NV * NCOL * sizeof(float);  // ~5.3 MB
  const size_t part_bytes = (size_t)NV * sizeof(float);         // ~27.5 KB
  const int grid = (NV + 3) / 4;

  if (ws_size >= xt_bytes + part_bytes) {
    float* Xt       = (float*)d_ws;
    float* partials = (float*)((char*)d_ws + xt_bytes);
    const int total = NB * NV * 3;
    transpose_x_kernel<<<(total + 255) / 256, 256, 0, stream>>>(x, Xt);
    lap_rows_wave_kernel<true, true><<<grid, 256, 0, stream>>>(L, Xt, partials, nullptr);
    reduce_kernel<<<1, 256, 0, stream>>>(partials, out);
  } else if (ws_size >= part_bytes) {
    float* partials = (float*)d_ws;
    lap_rows_wave_kernel<false, true><<<grid, 256, 0, stream>>>(L, x, partials, nullptr);
    reduce_kernel<<<1, 256, 0, stream>>>(partials, out);
  } else {
    zero_out_kernel<<<1, 64, 0, stream>>>(out);
    lap_rows_wave_kernel<false, false><<<grid, 256, 0, stream>>>(L, x, nullptr, out);
  }
}